// Round 15
// baseline (674.350 us; speedup 1.0000x reference)
//
#include <hip/hip_runtime.h>

typedef unsigned short u16;
typedef unsigned int u32;
typedef __attribute__((ext_vector_type(8))) short short8;
typedef __attribute__((ext_vector_type(4))) short short4v;
typedef __attribute__((ext_vector_type(4))) float f32x4;
typedef __attribute__((ext_vector_type(4))) float float4v;
typedef __attribute__((ext_vector_type(2))) u32 u32x2;
typedef __attribute__((ext_vector_type(4))) u32 u32x4;

#define S_LEN 8192
#define NHEAD 8
#define NBLK  128
#define SCALE_C 0.18033688011112042f   // log2(e)/sqrt(64), folded into stored q

__device__ __forceinline__ u16 f2b(float f) {
    union { float f; unsigned u; } v; v.f = f;
    unsigned r = v.u + 0x7FFFu + ((v.u >> 16) & 1u);
    return (u16)(r >> 16);
}
__device__ __forceinline__ float b2f(u16 b) {
    union { float f; unsigned u; } v; v.u = ((unsigned)b) << 16; return v.f;
}
__device__ __forceinline__ u32 cvt_pk_bf16(float lo, float hi) {
    u32 r;
    asm("v_cvt_pk_bf16_f32 %0, %1, %2" : "=v"(r) : "v"(lo), "v"(hi));
    return r;
}
// dual-result permlane swaps (verified round 4)
__device__ __forceinline__ void pl16swap(u32& a, u32& b) {
    u32x2 r = __builtin_amdgcn_permlane16_swap(a, b, false, false);
    a = r[0]; b = r[1];
}
__device__ __forceinline__ void pl32swap(u32& a, u32& b) {
    u32x2 r = __builtin_amdgcn_permlane32_swap(a, b, false, false);
    a = r[0]; b = r[1];
}
// XOR swizzle for [row][128B] LDS tiles (read side) — GEMM cores only
__device__ __forceinline__ int swz(int row, int colByte) {
    return row * 128 + (colByte ^ ((row & 7) << 4));
}
// async global->LDS, 16B per lane; LDS dest = wave-uniform base + lane*16.
// NOTE (R10 lesson): keep the offset imm ZERO — nonzero offset is unverified for
// LDS-DMA on gfx950 and produced NaN (uninitialized LDS). Do offsets in the pointer.
__device__ __forceinline__ void gload_lds(const void* g, void* l) {
    __builtin_amdgcn_global_load_lds(
        (const __attribute__((address_space(1))) void*)g,
        (__attribute__((address_space(3))) void*)l, 16, 0, 0);
}

// ---------------- converts ----------------
__global__ __launch_bounds__(256) void cvt_x_kernel(const float* __restrict__ x, u16* __restrict__ xb) {
    int idx = blockIdx.x * 256 + threadIdx.x;
    float4v v = *((const float4v*)x + idx);
    short4v o;
    #pragma unroll
    for (int r = 0; r < 4; ++r) o[r] = (short)f2b(v[r]);
    *((short4v*)xb + idx) = o;
}

// w: [512][C] fp32  ->  wt: [C][512] bf16
__global__ __launch_bounds__(256) void cvt_T_kernel(const float* __restrict__ w, u16* __restrict__ wt, int C) {
    int idx = blockIdx.x * 256 + threadIdx.x;   // over C*512
    int r = idx & 511, cc = idx >> 9;
    wt[idx] = f2b(w[(size_t)r * C + cc]);
}

// sum 2 bf16 partial buffers -> bf16 (fp32 accumulate)
__global__ __launch_bounds__(256) void sum2_kernel(const u16* __restrict__ a0, const u16* __restrict__ a1,
                                                   u16* __restrict__ outb) {
    int idx = blockIdx.x * 256 + threadIdx.x;   // per short8
    short8 v0 = ((const short8*)a0)[idx];
    short8 v1 = ((const short8*)a1)[idx];
    short8 o;
    #pragma unroll
    for (int e = 0; e < 8; ++e) o[e] = (short)f2b(b2f((u16)v0[e]) + b2f((u16)v1[e]));
    ((short8*)outb)[idx] = o;
}

// ---------------- GEMM core (m97 structure): async global->LDS staging, pre-swizzled source ----------------
__device__ __forceinline__ void gemm128_core(const u16* __restrict__ A,
                                             const u16* __restrict__ Bt,
                                             int m0, int n0, char* As, char* Bs,
                                             f32x4 acc[4][4]) {
    const int tid = threadIdx.x;
    const int lane = tid & 63, wid = tid >> 6;
    const int q16 = lane >> 4, l16 = lane & 15;
    const int wm = wid >> 1, wn = wid & 1;
    #pragma unroll 1
    for (int kt = 0; kt < 8; ++kt) {
        const int k0 = kt * 64;
        __syncthreads();   // previous compute done reading LDS
        #pragma unroll
        for (int p = 0; p < 4; ++p) {
            int c = tid + p * 256;
            int row = c >> 3, colp = (c & 7) ^ (row & 7);   // inverse-swizzled source col
            gload_lds(A  + (size_t)(m0 + row) * 512 + k0 + colp * 8, As + (size_t)(wid * 64 + p * 256) * 16);
            gload_lds(Bt + (size_t)(n0 + row) * 512 + k0 + colp * 8, Bs + (size_t)(wid * 64 + p * 256) * 16);
        }
        __syncthreads();   // drains vmcnt: tiles resident
        #pragma unroll
        for (int kk = 0; kk < 2; ++kk) {
            short8 a[4], b[4];
            #pragma unroll
            for (int t = 0; t < 4; ++t) {
                int arow = wm * 64 + t * 16 + l16;
                a[t] = *(const short8*)(As + swz(arow, kk * 64 + q16 * 16));
                int brow = wn * 64 + t * 16 + l16;
                b[t] = *(const short8*)(Bs + swz(brow, kk * 64 + q16 * 16));
            }
            #pragma unroll
            for (int mt = 0; mt < 4; ++mt)
                #pragma unroll
                for (int nt = 0; nt < 4; ++nt)
                    acc[mt][nt] = __builtin_amdgcn_mfma_f32_16x16x32_bf16(a[mt], b[nt], acc[mt][nt], 0, 0, 0);
        }
    }
}

// QKV GEMM epilogue:
//   q  -> [H][S][64] bf16, pre-scaled by SCALE_C
//   K  -> Kf[h][j][u] fragment-linear: u = (n0*2+c)*64 + q16*16 + l16, elem e;
//         element (key,d): n0=key>>4, l16=key&15, c=d>>5, q16=(d>>3)&3, e=d&7
//   V  -> Vf[h][j][u] fragment-linear: u = (dt*2+c)*64 + q16*16 + l16, elem e;
//         element (key,d): dt=d>>4, l16=d&15, c=key>>5, q16=(key>>3)&3, e=key&7
__global__ __launch_bounds__(256) void qkv_gemm(const u16* __restrict__ xb, const u16* __restrict__ wqkvT,
                                                const float* __restrict__ bqkv,
                                                u16* __restrict__ qb, u16* __restrict__ kf, u16* __restrict__ vf) {
    __shared__ char smem[32768];
    f32x4 acc[4][4];
    #pragma unroll
    for (int a = 0; a < 4; ++a)
        #pragma unroll
        for (int b = 0; b < 4; ++b) acc[a][b] = (f32x4){0.f, 0.f, 0.f, 0.f};
    const int m0 = blockIdx.x * 128, n0 = blockIdx.y * 128;
    gemm128_core(xb, wqkvT, m0, n0, smem, smem + 16384, acc);

    const int lane = threadIdx.x & 63, wid = threadIdx.x >> 6;
    const int q16 = lane >> 4, l16 = lane & 15;
    const int wm = wid >> 1, wn = wid & 1;
    #pragma unroll
    for (int mt = 0; mt < 4; ++mt) {
        #pragma unroll
        for (int nt = 0; nt < 4; ++nt) {
            int n = n0 + wn * 64 + nt * 16 + l16;
            float bias = bqkv[n];
            int t = n >> 9, h = (n >> 6) & 7, d = n & 63;
            int sb = m0 + wm * 64 + mt * 16 + q16 * 4;
            f32x4 v = acc[mt][nt];
            if (t == 0) {
                #pragma unroll
                for (int r = 0; r < 4; ++r)
                    qb[(size_t)(h * S_LEN + sb + r) * 64 + d] = f2b((v[r] + bias) * SCALE_C);
            } else if (t == 1) {
                int j = sb >> 6, key = sb & 63;
                int n0k = key >> 4, c = d >> 5, q16k = (d >> 3) & 3, e = d & 7;
                int ub = (n0k * 2 + c) * 64 + q16k * 16 + (key & 15);
                u16* base = kf + (size_t)h * 524288 + (size_t)j * 4096 + e;
                #pragma unroll
                for (int r = 0; r < 4; ++r)
                    base[(ub + r) * 8] = f2b(v[r] + bias);
            } else {
                int j = sb >> 6, key = sb & 63;
                int dt = d >> 4, c = key >> 5, q16v = (key >> 3) & 3, e0 = key & 7;
                int u = (dt * 2 + c) * 64 + q16v * 16 + (d & 15);
                short4v pk;
                #pragma unroll
                for (int r = 0; r < 4; ++r) pk[r] = (short)f2b(v[r] + bias);
                *(short4v*)(vf + (size_t)h * 524288 + (size_t)j * 4096 + u * 8 + e0) = pk;
            }
        }
    }
}

// out GEMM: fp32 out[s][n] = attn @ w_out + b_out
__global__ __launch_bounds__(256) void out_gemm(const u16* __restrict__ a0, const u16* __restrict__ wotT,
                                                const float* __restrict__ bout, float* __restrict__ out) {
    __shared__ char smem[32768];
    f32x4 acc[4][4];
    #pragma unroll
    for (int a = 0; a < 4; ++a)
        #pragma unroll
        for (int b = 0; b < 4; ++b) acc[a][b] = (f32x4){0.f, 0.f, 0.f, 0.f};
    const int m0 = blockIdx.x * 128, n0 = blockIdx.y * 128;
    gemm128_core(a0, wotT, m0, n0, smem, smem + 16384, acc);

    const int lane = threadIdx.x & 63, wid = threadIdx.x >> 6;
    const int q16 = lane >> 4, l16 = lane & 15;
    const int wm = wid >> 1, wn = wid & 1;
    #pragma unroll
    for (int mt = 0; mt < 4; ++mt) {
        #pragma unroll
        for (int nt = 0; nt < 4; ++nt) {
            int n = n0 + wn * 64 + nt * 16 + l16;
            float bias = bout[n];
            int sb = m0 + wm * 64 + mt * 16 + q16 * 4;
            #pragma unroll
            for (int r = 0; r < 4; ++r)
                out[(size_t)(sb + r) * 512 + n] = acc[mt][nt][r] + bias;
        }
    }
}

// ---------------- router (qb pre-scaled by SCALE_C; compensate in the mean) ----------------
// Phase 1 vectorized (G13): thread t = (h=t>>5, rs=(t>>3)&3, g=t&7) accumulates 16 rows
// of 8 contiguous d via short8 loads; 4 row-subset partials reduced through LDS.
__global__ __launch_bounds__(256) void router_kernel(const u16* __restrict__ qb,
                                                     const float* __restrict__ w_r1, const float* __restrict__ b_r1,
                                                     const float* __restrict__ w_r2, const float* __restrict__ b_r2,
                                                     float* __restrict__ keepf) {
    const int nb = blockIdx.x, tid = threadIdx.x;
    __shared__ float part[512][4];
    __shared__ float rep[512];
    __shared__ float h1[128];
    {
        int h = tid >> 5, rs = (tid >> 3) & 3, g = tid & 7;
        const u16* base = qb + (size_t)(h * S_LEN + nb * 64 + rs * 16) * 64 + g * 8;
        float acc[8] = {0.f, 0.f, 0.f, 0.f, 0.f, 0.f, 0.f, 0.f};
        #pragma unroll 4
        for (int r = 0; r < 16; ++r) {
            short8 v = *(const short8*)(base + (size_t)r * 64);
            #pragma unroll
            for (int e = 0; e < 8; ++e) acc[e] += b2f((u16)v[e]);
        }
        #pragma unroll
        for (int e = 0; e < 8; ++e) part[h * 64 + g * 8 + e][rs] = acc[e];
    }
    __syncthreads();
    for (int dim = tid; dim < 512; dim += 256)
        rep[dim] = (part[dim][0] + part[dim][1] + part[dim][2] + part[dim][3]) * (0.015625f / SCALE_C);
    __syncthreads();
    if (tid < 128) {
        float a = b_r1[tid];
        for (int k = 0; k < 512; ++k) a += rep[k] * w_r1[k * 128 + tid];
        h1[tid] = fmaxf(a, 0.f);
    }
    __syncthreads();
    if (tid < 64) {
        float v = h1[tid] * w_r2[tid] + h1[tid + 64] * w_r2[tid + 64];
        #pragma unroll
        for (int off = 32; off; off >>= 1) v += __shfl_down(v, off);
        if (tid == 0) {
            float z = v + b_r2[0];
            // sigmoid(z) >= 0.3  <=>  z >= ln(0.3/0.7)
            keepf[nb] = (z >= -0.84729786f) ? 1.0f : 0.0f;
        }
    }
}

// ---------------- block-sparse attention ----------------
// grid (8 heads, 2 j-halves, 64 q-tiles) — h is the FASTEST blockIdx dim, so with
// round-robin XCD assignment block%8==h: each XCD serves ONE head, whose K/V (2MB)
// fits its private L2 (T1; was 82MB FETCH from 8x panel replication).
// T15 pipeline + 2-deep K ring + 2-deep V ring = 32KB LDS -> 5 blocks/CU (20 waves).
// Schedule per body jj: WAITBAR (drain K(jj+1),V(jj)) -> stage K(jj+2) over K(jj),
// V(jj+1) over V(jj-1) -> QK(K(jj+1)) [overlaps softmax on the MFMA pipe] ->
// softmax+PV(jj). Overwritten slots' ds_reads were consumed by MFMAs (lgkm-forced)
// before the intervening barrier — same hazard guarantee as the 3-ring versions.
__global__ __launch_bounds__(256, 5) void attn_kernel(const u16* __restrict__ qb, const u16* __restrict__ kf,
                                                      const u16* __restrict__ vf, const float* __restrict__ keepf,
                                                      u16* __restrict__ a0, u16* __restrict__ a1, int nj) {
    const int h = blockIdx.x, jh = blockIdx.y, i = blockIdx.z;
    const int j0 = jh * nj;
    u16* __restrict__ att = jh ? a1 : a0;
    const int tid = threadIdx.x, lane = tid & 63, wid = tid >> 6;
    const int q16 = lane >> 4, l16 = lane & 15;
    __shared__ char smem[32768];   // K ring 2x8K | V ring 2x8K (fragment-linear)

    // Q fragments: 2 q-sub-tiles of 16 per wave
    short8 bq[2][2];
    #pragma unroll
    for (int qh = 0; qh < 2; ++qh) {
        const u16* qrow = qb + (size_t)(h * S_LEN + i * 128 + wid * 32 + qh * 16 + l16) * 64;
        bq[qh][0] = *(const short8*)(qrow + q16 * 8);
        bq[qh][1] = *(const short8*)(qrow + 32 + q16 * 8);
    }
    const int kq_s = __builtin_amdgcn_readfirstlane(i * 2 + (wid >> 1));  // wave-uniform 64-q block idx
    const float keep_i = keepf[kq_s];
    // preload gate values: lane L holds keepf[j0 + L] (nj=64: exact cover)
    const u32 kvbits = __builtin_bit_cast(u32, keepf[(j0 + lane) & 127]);
    const int qloc = (wid & 1) * 32 + l16;      // q within its 64-block, minus qh*16

    f32x4 o[2][4];
    #pragma unroll
    for (int qh = 0; qh < 2; ++qh)
        #pragma unroll
        for (int t = 0; t < 4; ++t) o[qh][t] = (f32x4){0.f, 0.f, 0.f, 0.f};

    const int lb = lane * 16;                    // ds_read lane offset (bytes)
    const int stoff = (wid * 128 + lane) * 8;    // staging source offset (u16)
    const int ldw = wid * 2048;                  // staging LDS base (bytes)

    const u16* kst = kf + (size_t)h * 524288 + stoff + (size_t)j0 * 4096;
    const u16* vst = vf + (size_t)h * 524288 + stoff + (size_t)j0 * 4096;
    char *kStage = smem, *kRead = smem + 8192;       // prologue: K(0)->kStage, K(1)->kRead
    char *vCur = smem + 16384, *vStage = smem + 24576;

    // drain pre-loop VMEM (bq, keep_i, kvbits) so staging vmcnt counts are exact
    asm volatile("s_waitcnt vmcnt(0)" ::: "memory");

    auto STAGE_K = [&](char* dst) {
        gload_lds(kst, dst + ldw);   gload_lds(kst + 512, dst + ldw + 1024);
        kst += 4096;
    };
    auto STAGE_V = [&](char* dst) {
        gload_lds(vst, dst + ldw);   gload_lds(vst + 512, dst + ldw + 1024);
        vst += 4096;
    };
    // QK^T of the tile in Kc into s (pure MFMA + ds_read)
    auto QK = [&](const char* Kc, f32x4 (&s)[2][4]) {
        __builtin_amdgcn_s_setprio(1);
        #pragma unroll
        for (int n0 = 0; n0 < 4; ++n0) {
            short8 ka0 = *(const short8*)(Kc + n0 * 2048 + lb);
            short8 ka1 = *(const short8*)(Kc + n0 * 2048 + 1024 + lb);
            #pragma unroll
            for (int qh = 0; qh < 2; ++qh) {
                f32x4 a = (f32x4){0.f, 0.f, 0.f, 0.f};
                a = __builtin_amdgcn_mfma_f32_16x16x32_bf16(ka0, bq[qh][0], a, 0, 0, 0);
                a = __builtin_amdgcn_mfma_f32_16x16x32_bf16(ka1, bq[qh][1], a, 0, 0, 0);
                s[qh][n0] = a;
            }
        }
        __builtin_amdgcn_s_setprio(0);
    };
    // softmax(tile jjl) from s + PV accumulate from Vc
    auto SMPV = [&](int jjl, const f32x4 (&s)[2][4], const char* Vc) {
        const float kj = __builtin_bit_cast(float, (u32)__builtin_amdgcn_readlane((int)kvbits, jjl));
        const float gj = keep_i * kj;
        const int j = j0 + jjl;
        short8 pb[2][2];
        #pragma unroll
        for (int qh = 0; qh < 2; ++qh) {
            f32x4 p4[4];
            #pragma unroll
            for (int n0 = 0; n0 < 4; ++n0)
                #pragma unroll
                for (int r = 0; r < 4; ++r)
                    p4[n0][r] = __builtin_amdgcn_exp2f(s[qh][n0][r]);
            if (j == kq_s) {   // scalar branch: strict upper triangle inside diagonal block
                const int qthis = qloc + qh * 16;
                #pragma unroll
                for (int n0 = 0; n0 < 4; ++n0)
                    #pragma unroll
                    for (int r = 0; r < 4; ++r)
                        if (n0 * 16 + q16 * 4 + r > qthis) p4[n0][r] = 0.f;
            }
            f32x4 sv = (p4[0] + p4[1]) + (p4[2] + p4[3]);
            float sum = (sv[0] + sv[1]) + (sv[2] + sv[3]);
            {   // butterfly over the 4 q16-groups
                u32 sa = __builtin_bit_cast(u32, sum), sb = sa;
                pl16swap(sa, sb);
                sum = __builtin_bit_cast(float, sa) + __builtin_bit_cast(float, sb);
                u32 sc = __builtin_bit_cast(u32, sum), sd = sc;
                pl32swap(sc, sd);
                sum = __builtin_bit_cast(float, sc) + __builtin_bit_cast(float, sd);
            }
            const float rinv = gj * __builtin_amdgcn_rcpf(sum);
            u32 dw[4][2];
            #pragma unroll
            for (int n0 = 0; n0 < 4; ++n0) {
                f32x4 t = p4[n0] * rinv;
                dw[n0][0] = cvt_pk_bf16(t[0], t[1]);
                dw[n0][1] = cvt_pk_bf16(t[2], t[3]);
            }
            #pragma unroll
            for (int kk = 0; kk < 2; ++kk) {
                u32 c0 = dw[2 * kk][0], d0 = dw[2 * kk + 1][0];
                pl32swap(c0, d0);
                pl16swap(c0, d0);
                u32 c1 = dw[2 * kk][1], d1 = dw[2 * kk + 1][1];
                pl32swap(c1, d1);
                pl16swap(c1, d1);
                u32x4 wv;
                wv[0] = c0; wv[1] = c1; wv[2] = d0; wv[3] = d1;
                pb[qh][kk] = __builtin_bit_cast(short8, wv);
            }
        }
        __builtin_amdgcn_s_setprio(1);
        #pragma unroll
        for (int dt = 0; dt < 4; ++dt) {
            short8 va0 = *(const short8*)(Vc + dt * 2048 + lb);
            short8 va1 = *(const short8*)(Vc + dt * 2048 + 1024 + lb);
            #pragma unroll
            for (int qh = 0; qh < 2; ++qh) {
                o[qh][dt] = __builtin_amdgcn_mfma_f32_16x16x32_bf16(va0, pb[qh][0], o[qh][dt], 0, 0, 0);
                o[qh][dt] = __builtin_amdgcn_mfma_f32_16x16x32_bf16(va1, pb[qh][1], o[qh][dt], 0, 0, 0);
            }
        }
        __builtin_amdgcn_s_setprio(0);
    };
    auto WAITBAR = [&]() {
        asm volatile("s_waitcnt vmcnt(0)" ::: "memory");
        __builtin_amdgcn_s_barrier();
        __builtin_amdgcn_sched_barrier(0);
    };
    auto ROT = [&]() {
        char* t = kRead; kRead = kStage; kStage = t;
        char* u = vCur; vCur = vStage; vStage = u;
    };

    // prologue: K(0)->kStage, V(0)->vCur, K(1)->kRead; QK(0) from kStage
    STAGE_K(kStage);
    STAGE_V(vCur);
    STAGE_K(kRead);
    asm volatile("s_waitcnt vmcnt(2)" ::: "memory");   // K(0), V(0) resident; K(1) in flight
    __builtin_amdgcn_s_barrier();

    f32x4 sA[2][4], sB[2][4];
    QK(kStage, sA);

    // main loop: bodies 0 .. nj-3 (2x unrolled, static sA/sB ping-pong)
    for (int jj = 0; jj + 3 < nj; jj += 2) {
        WAITBAR();               // K(jj+1), V(jj) resident (all waves)
        STAGE_K(kStage);         // K(jj+2) over K(jj)  (QK readers done pre-barrier)
        STAGE_V(vStage);         // V(jj+1) over V(jj-1) (PV readers done pre-barrier)
        QK(kRead, sB);           // QK(tile jj+1) — overlaps softmax below
        SMPV(jj, sA, vCur);      // softmax+PV of tile jj
        ROT();
        WAITBAR();
        STAGE_K(kStage);         // K(jj+3)
        STAGE_V(vStage);         // V(jj+2)
        QK(kRead, sA);
        SMPV(jj + 1, sB, vCur);
        ROT();
    }
    // body nj-2: stage V(nj-1) only (K(nj) doesn't exist)
    WAITBAR();
    STAGE_V(vStage);
    QK(kRead, sB);
    SMPV(nj - 2, sA, vCur);
    ROT();
    // body nj-1: softmax+PV only
    WAITBAR();
    SMPV(nj - 1, sB, vCur);

    // epilogue: att[q][h*64 + d], d = dt*16 + q16*4 + r -> packed 8B stores
    #pragma unroll
    for (int qh = 0; qh < 2; ++qh) {
        u16* obase = att + (size_t)(i * 128 + wid * 32 + qh * 16 + l16) * 512 + h * 64 + q16 * 4;
        #pragma unroll
        for (int dt = 0; dt < 4; ++dt) {
            u32x2 st;
            st[0] = cvt_pk_bf16(o[qh][dt][0], o[qh][dt][1]);
            st[1] = cvt_pk_bf16(o[qh][dt][2], o[qh][dt][3]);
            *(u32x2*)(obase + dt * 16) = st;
        }
    }
}

// ---------------- workspace layout (bytes); peak 43 MiB + keep ----------------
// wqkvT 0..2M | wotT 2..2.5M | keep 2.5M | qb 3..11M (attnb alias after attn) |
// kf 11..19M | vf 19..27M | xb 27..35M (dead after qkv; att1 alias) | att0 35..43M
static const size_t OFF_WQKVT = 0;
static const size_t OFF_WOTT  = (size_t)2u << 20;
static const size_t OFF_KEEP  = ((size_t)2u << 20) + (512u << 10);
static const size_t OFF_QB    = (size_t)3u << 20;
static const size_t OFF_KF    = (size_t)11u << 20;
static const size_t OFF_VF    = (size_t)19u << 20;
static const size_t OFF_XB    = (size_t)27u << 20;
static const size_t OFF_P0    = (size_t)35u << 20;

extern "C" void kernel_launch(void* const* d_in, const int* in_sizes, int n_in,
                              void* d_out, int out_size, void* d_ws, size_t ws_size,
                              hipStream_t stream) {
    const float* x     = (const float*)d_in[0];
    const float* w_qkv = (const float*)d_in[1];
    const float* b_qkv = (const float*)d_in[2];
    const float* w_out = (const float*)d_in[3];
    const float* b_out = (const float*)d_in[4];
    const float* w_r1  = (const float*)d_in[5];
    const float* b_r1  = (const float*)d_in[6];
    const float* w_r2  = (const float*)d_in[7];
    const float* b_r2  = (const float*)d_in[8];
    float* out = (float*)d_out;
    char* ws = (char*)d_ws;
    u16* wqkvT  = (u16*)(ws + OFF_WQKVT);
    u16* wotT   = (u16*)(ws + OFF_WOTT);
    float* keepf = (float*)(ws + OFF_KEEP);
    u16* qb     = (u16*)(ws + OFF_QB);
    u16* kf     = (u16*)(ws + OFF_KF);
    u16* vf     = (u16*)(ws + OFF_VF);
    u16* xb     = (u16*)(ws + OFF_XB);
    u16* attnb  = (u16*)(ws + OFF_QB);   // alias: qb dead after attn
    u16* a0     = (u16*)(ws + OFF_P0);
    u16* a1     = (u16*)(ws + OFF_XB);   // alias: xb dead after qkv_gemm

    cvt_x_kernel<<<4096, 256, 0, stream>>>(x, xb);
    cvt_T_kernel<<<3072, 256, 0, stream>>>(w_qkv, wqkvT, 1536);
    cvt_T_kernel<<<1024, 256, 0, stream>>>(w_out, wotT, 512);
    qkv_gemm<<<dim3(64, 12), 256, 0, stream>>>(xb, wqkvT, b_qkv, qb, kf, vf);
    router_kernel<<<128, 256, 0, stream>>>(qb, w_r1, b_r1, w_r2, b_r2, keepf);
    attn_kernel<<<dim3(8, 2, 64), 256, 0, stream>>>(qb, kf, vf, keepf, a0, a1, 64);
    sum2_kernel<<<2048, 256, 0, stream>>>(a0, a1, attnb);
    out_gemm<<<dim3(64, 4), 256, 0, stream>>>(attnb, wotT, b_out, out);
}

// Round 16
// 232.528 us; speedup vs baseline: 2.9001x; 2.9001x over previous
//
#include <hip/hip_runtime.h>

typedef unsigned short u16;
typedef unsigned int u32;
typedef __attribute__((ext_vector_type(8))) short short8;
typedef __attribute__((ext_vector_type(4))) short short4v;
typedef __attribute__((ext_vector_type(4))) float f32x4;
typedef __attribute__((ext_vector_type(4))) float float4v;
typedef __attribute__((ext_vector_type(2))) u32 u32x2;
typedef __attribute__((ext_vector_type(4))) u32 u32x4;

#define S_LEN 8192
#define NHEAD 8
#define NBLK  128
#define SCALE_C 0.18033688011112042f   // log2(e)/sqrt(64), folded into stored q

__device__ __forceinline__ u16 f2b(float f) {
    union { float f; unsigned u; } v; v.f = f;
    unsigned r = v.u + 0x7FFFu + ((v.u >> 16) & 1u);
    return (u16)(r >> 16);
}
__device__ __forceinline__ float b2f(u16 b) {
    union { float f; unsigned u; } v; v.u = ((unsigned)b) << 16; return v.f;
}
__device__ __forceinline__ u32 cvt_pk_bf16(float lo, float hi) {
    u32 r;
    asm("v_cvt_pk_bf16_f32 %0, %1, %2" : "=v"(r) : "v"(lo), "v"(hi));
    return r;
}
// dual-result permlane swaps (verified round 4)
__device__ __forceinline__ void pl16swap(u32& a, u32& b) {
    u32x2 r = __builtin_amdgcn_permlane16_swap(a, b, false, false);
    a = r[0]; b = r[1];
}
__device__ __forceinline__ void pl32swap(u32& a, u32& b) {
    u32x2 r = __builtin_amdgcn_permlane32_swap(a, b, false, false);
    a = r[0]; b = r[1];
}
// XOR swizzle for [row][128B] LDS tiles (read side) — GEMM cores only
__device__ __forceinline__ int swz(int row, int colByte) {
    return row * 128 + (colByte ^ ((row & 7) << 4));
}
// async global->LDS, 16B per lane; LDS dest = wave-uniform base + lane*16.
// NOTE (R10 lesson): keep the offset imm ZERO — nonzero offset is unverified for
// LDS-DMA on gfx950 and produced NaN (uninitialized LDS). Do offsets in the pointer.
__device__ __forceinline__ void gload_lds(const void* g, void* l) {
    __builtin_amdgcn_global_load_lds(
        (const __attribute__((address_space(1))) void*)g,
        (__attribute__((address_space(3))) void*)l, 16, 0, 0);
}

// ---------------- converts ----------------
__global__ __launch_bounds__(256) void cvt_x_kernel(const float* __restrict__ x, u16* __restrict__ xb) {
    int idx = blockIdx.x * 256 + threadIdx.x;
    float4v v = *((const float4v*)x + idx);
    short4v o;
    #pragma unroll
    for (int r = 0; r < 4; ++r) o[r] = (short)f2b(v[r]);
    *((short4v*)xb + idx) = o;
}

// w: [512][C] fp32  ->  wt: [C][512] bf16
__global__ __launch_bounds__(256) void cvt_T_kernel(const float* __restrict__ w, u16* __restrict__ wt, int C) {
    int idx = blockIdx.x * 256 + threadIdx.x;   // over C*512
    int r = idx & 511, cc = idx >> 9;
    wt[idx] = f2b(w[(size_t)r * C + cc]);
}

// sum n (2 or 4) bf16 partial buffers -> bf16 (fp32 accumulate)
__global__ __launch_bounds__(256) void sum4_kernel(const u16* __restrict__ a0, const u16* __restrict__ a1,
                                                   const u16* __restrict__ a2, const u16* __restrict__ a3,
                                                   int n, u16* __restrict__ outb) {
    int idx = blockIdx.x * 256 + threadIdx.x;   // per short8
    short8 v0 = ((const short8*)a0)[idx];
    short8 v1 = ((const short8*)a1)[idx];
    float s[8];
    #pragma unroll
    for (int e = 0; e < 8; ++e) s[e] = b2f((u16)v0[e]) + b2f((u16)v1[e]);
    if (n == 4) {
        short8 v2 = ((const short8*)a2)[idx];
        short8 v3 = ((const short8*)a3)[idx];
        #pragma unroll
        for (int e = 0; e < 8; ++e) s[e] += b2f((u16)v2[e]) + b2f((u16)v3[e]);
    }
    short8 o;
    #pragma unroll
    for (int e = 0; e < 8; ++e) o[e] = (short)f2b(s[e]);
    ((short8*)outb)[idx] = o;
}

// ---------------- GEMM core (m97 structure): async global->LDS staging, pre-swizzled source ----------------
__device__ __forceinline__ void gemm128_core(const u16* __restrict__ A,
                                             const u16* __restrict__ Bt,
                                             int m0, int n0, char* As, char* Bs,
                                             f32x4 acc[4][4]) {
    const int tid = threadIdx.x;
    const int lane = tid & 63, wid = tid >> 6;
    const int q16 = lane >> 4, l16 = lane & 15;
    const int wm = wid >> 1, wn = wid & 1;
    #pragma unroll 1
    for (int kt = 0; kt < 8; ++kt) {
        const int k0 = kt * 64;
        __syncthreads();   // previous compute done reading LDS
        #pragma unroll
        for (int p = 0; p < 4; ++p) {
            int c = tid + p * 256;
            int row = c >> 3, colp = (c & 7) ^ (row & 7);   // inverse-swizzled source col
            gload_lds(A  + (size_t)(m0 + row) * 512 + k0 + colp * 8, As + (size_t)(wid * 64 + p * 256) * 16);
            gload_lds(Bt + (size_t)(n0 + row) * 512 + k0 + colp * 8, Bs + (size_t)(wid * 64 + p * 256) * 16);
        }
        __syncthreads();   // drains vmcnt: tiles resident
        #pragma unroll
        for (int kk = 0; kk < 2; ++kk) {
            short8 a[4], b[4];
            #pragma unroll
            for (int t = 0; t < 4; ++t) {
                int arow = wm * 64 + t * 16 + l16;
                a[t] = *(const short8*)(As + swz(arow, kk * 64 + q16 * 16));
                int brow = wn * 64 + t * 16 + l16;
                b[t] = *(const short8*)(Bs + swz(brow, kk * 64 + q16 * 16));
            }
            #pragma unroll
            for (int mt = 0; mt < 4; ++mt)
                #pragma unroll
                for (int nt = 0; nt < 4; ++nt)
                    acc[mt][nt] = __builtin_amdgcn_mfma_f32_16x16x32_bf16(a[mt], b[nt], acc[mt][nt], 0, 0, 0);
        }
    }
}

// QKV GEMM epilogue:
//   q  -> [H][S][64] bf16, pre-scaled by SCALE_C
//   K  -> Kf[h][j][u] fragment-linear: u = (n0*2+c)*64 + q16*16 + l16, elem e;
//         element (key,d): n0=key>>4, l16=key&15, c=d>>5, q16=(d>>3)&3, e=d&7
//   V  -> Vf[h][j][u] fragment-linear: u = (dt*2+c)*64 + q16*16 + l16, elem e;
//         element (key,d): dt=d>>4, l16=d&15, c=key>>5, q16=(key>>3)&3, e=key&7
__global__ __launch_bounds__(256) void qkv_gemm(const u16* __restrict__ xb, const u16* __restrict__ wqkvT,
                                                const float* __restrict__ bqkv,
                                                u16* __restrict__ qb, u16* __restrict__ kf, u16* __restrict__ vf) {
    __shared__ char smem[32768];
    f32x4 acc[4][4];
    #pragma unroll
    for (int a = 0; a < 4; ++a)
        #pragma unroll
        for (int b = 0; b < 4; ++b) acc[a][b] = (f32x4){0.f, 0.f, 0.f, 0.f};
    const int m0 = blockIdx.x * 128, n0 = blockIdx.y * 128;
    gemm128_core(xb, wqkvT, m0, n0, smem, smem + 16384, acc);

    const int lane = threadIdx.x & 63, wid = threadIdx.x >> 6;
    const int q16 = lane >> 4, l16 = lane & 15;
    const int wm = wid >> 1, wn = wid & 1;
    #pragma unroll
    for (int mt = 0; mt < 4; ++mt) {
        #pragma unroll
        for (int nt = 0; nt < 4; ++nt) {
            int n = n0 + wn * 64 + nt * 16 + l16;
            float bias = bqkv[n];
            int t = n >> 9, h = (n >> 6) & 7, d = n & 63;
            int sb = m0 + wm * 64 + mt * 16 + q16 * 4;
            f32x4 v = acc[mt][nt];
            if (t == 0) {
                #pragma unroll
                for (int r = 0; r < 4; ++r)
                    qb[(size_t)(h * S_LEN + sb + r) * 64 + d] = f2b((v[r] + bias) * SCALE_C);
            } else if (t == 1) {
                int j = sb >> 6, key = sb & 63;
                int n0k = key >> 4, c = d >> 5, q16k = (d >> 3) & 3, e = d & 7;
                int ub = (n0k * 2 + c) * 64 + q16k * 16 + (key & 15);
                u16* base = kf + (size_t)h * 524288 + (size_t)j * 4096 + e;
                #pragma unroll
                for (int r = 0; r < 4; ++r)
                    base[(ub + r) * 8] = f2b(v[r] + bias);
            } else {
                int j = sb >> 6, key = sb & 63;
                int dt = d >> 4, c = key >> 5, q16v = (key >> 3) & 3, e0 = key & 7;
                int u = (dt * 2 + c) * 64 + q16v * 16 + (d & 15);
                short4v pk;
                #pragma unroll
                for (int r = 0; r < 4; ++r) pk[r] = (short)f2b(v[r] + bias);
                *(short4v*)(vf + (size_t)h * 524288 + (size_t)j * 4096 + u * 8 + e0) = pk;
            }
        }
    }
}

// out GEMM: fp32 out[s][n] = attn @ w_out + b_out
__global__ __launch_bounds__(256) void out_gemm(const u16* __restrict__ a0, const u16* __restrict__ wotT,
                                                const float* __restrict__ bout, float* __restrict__ out) {
    __shared__ char smem[32768];
    f32x4 acc[4][4];
    #pragma unroll
    for (int a = 0; a < 4; ++a)
        #pragma unroll
        for (int b = 0; b < 4; ++b) acc[a][b] = (f32x4){0.f, 0.f, 0.f, 0.f};
    const int m0 = blockIdx.x * 128, n0 = blockIdx.y * 128;
    gemm128_core(a0, wotT, m0, n0, smem, smem + 16384, acc);

    const int lane = threadIdx.x & 63, wid = threadIdx.x >> 6;
    const int q16 = lane >> 4, l16 = lane & 15;
    const int wm = wid >> 1, wn = wid & 1;
    #pragma unroll
    for (int mt = 0; mt < 4; ++mt) {
        #pragma unroll
        for (int nt = 0; nt < 4; ++nt) {
            int n = n0 + wn * 64 + nt * 16 + l16;
            float bias = bout[n];
            int sb = m0 + wm * 64 + mt * 16 + q16 * 4;
            #pragma unroll
            for (int r = 0; r < 4; ++r)
                out[(size_t)(sb + r) * 512 + n] = acc[mt][nt][r] + bias;
        }
    }
}

// ---------------- router (qb pre-scaled by SCALE_C; compensate in the mean) ----------------
// Phase 1 vectorized (G13): thread t = (h=t>>5, rs=(t>>3)&3, g=t&7) accumulates 16 rows
// of 8 contiguous d via short8 loads; 4 row-subset partials reduced through LDS.
__global__ __launch_bounds__(256) void router_kernel(const u16* __restrict__ qb,
                                                     const float* __restrict__ w_r1, const float* __restrict__ b_r1,
                                                     const float* __restrict__ w_r2, const float* __restrict__ b_r2,
                                                     float* __restrict__ keepf) {
    const int nb = blockIdx.x, tid = threadIdx.x;
    __shared__ float part[512][4];
    __shared__ float rep[512];
    __shared__ float h1[128];
    {
        int h = tid >> 5, rs = (tid >> 3) & 3, g = tid & 7;
        const u16* base = qb + (size_t)(h * S_LEN + nb * 64 + rs * 16) * 64 + g * 8;
        float acc[8] = {0.f, 0.f, 0.f, 0.f, 0.f, 0.f, 0.f, 0.f};
        #pragma unroll 4
        for (int r = 0; r < 16; ++r) {
            short8 v = *(const short8*)(base + (size_t)r * 64);
            #pragma unroll
            for (int e = 0; e < 8; ++e) acc[e] += b2f((u16)v[e]);
        }
        #pragma unroll
        for (int e = 0; e < 8; ++e) part[h * 64 + g * 8 + e][rs] = acc[e];
    }
    __syncthreads();
    for (int dim = tid; dim < 512; dim += 256)
        rep[dim] = (part[dim][0] + part[dim][1] + part[dim][2] + part[dim][3]) * (0.015625f / SCALE_C);
    __syncthreads();
    if (tid < 128) {
        float a = b_r1[tid];
        for (int k = 0; k < 512; ++k) a += rep[k] * w_r1[k * 128 + tid];
        h1[tid] = fmaxf(a, 0.f);
    }
    __syncthreads();
    if (tid < 64) {
        float v = h1[tid] * w_r2[tid] + h1[tid + 64] * w_r2[tid + 64];
        #pragma unroll
        for (int off = 32; off; off >>= 1) v += __shfl_down(v, off);
        if (tid == 0) {
            float z = v + b_r2[0];
            // sigmoid(z) >= 0.3  <=>  z >= ln(0.3/0.7)
            keepf[nb] = (z >= -0.84729786f) ? 1.0f : 0.0f;
        }
    }
}

// ---------------- block-sparse attention ----------------
// grid (8 heads FASTEST, njh j-splits, 64 q-tiles): linear block id % 8 == h under
// round-robin XCD dispatch, so each XCD's private L2 serves exactly ONE head's K/V
// panel (2 MB, fits 4 MB L2) — T1 fix for R14's 82 MB FETCH (8x panel replication).
// Compute kernel is byte-identical to R14 (174.5us, VGPR 64, no spill): T15 pipeline,
// split K(2)/V(3) LDS rings = 40 KB, __launch_bounds__(256,4). R15 lesson: (256,5)
// caps VGPR at ~96 < the ~130 live values -> loop spill (3.2 GB scratch traffic);
// occupancy is VGPR-bound at 4 blocks/CU, so don't squeeze LDS below 40 KB.
__global__ __launch_bounds__(256, 4) void attn_kernel(const u16* __restrict__ qb, const u16* __restrict__ kf,
                                                      const u16* __restrict__ vf, const float* __restrict__ keepf,
                                                      u16* __restrict__ a0, u16* __restrict__ a1,
                                                      u16* __restrict__ a2, u16* __restrict__ a3, int nj) {
    const int h = blockIdx.x, jh = blockIdx.y, i = blockIdx.z;
    const int j0 = jh * nj;
    u16* __restrict__ att = (jh == 0) ? a0 : (jh == 1) ? a1 : (jh == 2) ? a2 : a3;
    const int tid = threadIdx.x, lane = tid & 63, wid = tid >> 6;
    const int q16 = lane >> 4, l16 = lane & 15;
    __shared__ char smem[40960];   // K ring: 2 x 8K | V ring: 3 x 8K (fragment-linear)

    // Q fragments: 2 q-sub-tiles of 16 per wave
    short8 bq[2][2];
    #pragma unroll
    for (int qh = 0; qh < 2; ++qh) {
        const u16* qrow = qb + (size_t)(h * S_LEN + i * 128 + wid * 32 + qh * 16 + l16) * 64;
        bq[qh][0] = *(const short8*)(qrow + q16 * 8);
        bq[qh][1] = *(const short8*)(qrow + 32 + q16 * 8);
    }
    const int kq_s = __builtin_amdgcn_readfirstlane(i * 2 + (wid >> 1));  // wave-uniform 64-q block idx
    const float keep_i = keepf[kq_s];
    // preload gate values: lane L holds keepf[j0 + L] (wrapped in-bounds)
    const u32 kvbits = __builtin_bit_cast(u32, keepf[(j0 + lane) & 127]);
    const int qloc = (wid & 1) * 32 + l16;      // q within its 64-block, minus qh*16

    f32x4 o[2][4];
    #pragma unroll
    for (int qh = 0; qh < 2; ++qh)
        #pragma unroll
        for (int t = 0; t < 4; ++t) o[qh][t] = (f32x4){0.f, 0.f, 0.f, 0.f};

    const int lb = lane * 16;                    // ds_read lane offset (bytes)
    const int stoff = (wid * 128 + lane) * 8;    // staging source offset (u16)
    const int ldw = wid * 2048;                  // staging LDS base (bytes)

    const u16* kst = kf + (size_t)h * 524288 + stoff + (size_t)j0 * 4096;
    const u16* vst = vf + (size_t)h * 524288 + stoff + (size_t)j0 * 4096;
    // K ring (2) and V ring (3)
    char *kRead = smem + 8192, *kStage = smem;               // after prologue: kRead=K(1), kStage holds K(0)
    char *vPV = smem + 16384, *vNext = smem + 24576, *vStage = smem + 32768;

    // drain pre-loop VMEM (bq, keep_i, kvbits) so staging vmcnt counts are exact
    asm volatile("s_waitcnt vmcnt(0)" ::: "memory");

    // stage tile at kst/vst into (kdst, vdst), advance pointers
    auto STAGE = [&](char* kdst, char* vdst) {
        gload_lds(kst,       kdst + ldw);   gload_lds(kst + 512, kdst + ldw + 1024);
        gload_lds(vst,       vdst + ldw);   gload_lds(vst + 512, vdst + ldw + 1024);
        kst += 4096; vst += 4096;
    };
    // QK^T of the tile in Kc into s (pure MFMA + ds_read; no dependence on softmax state)
    auto QK = [&](const char* Kc, f32x4 (&s)[2][4]) {
        __builtin_amdgcn_s_setprio(1);
        #pragma unroll
        for (int n0 = 0; n0 < 4; ++n0) {
            short8 ka0 = *(const short8*)(Kc + n0 * 2048 + lb);
            short8 ka1 = *(const short8*)(Kc + n0 * 2048 + 1024 + lb);
            #pragma unroll
            for (int qh = 0; qh < 2; ++qh) {
                f32x4 a = (f32x4){0.f, 0.f, 0.f, 0.f};
                a = __builtin_amdgcn_mfma_f32_16x16x32_bf16(ka0, bq[qh][0], a, 0, 0, 0);
                a = __builtin_amdgcn_mfma_f32_16x16x32_bf16(ka1, bq[qh][1], a, 0, 0, 0);
                s[qh][n0] = a;
            }
        }
        __builtin_amdgcn_s_setprio(0);
    };
    // softmax(tile jjl) from s + PV accumulate from Vc
    auto SMPV = [&](int jjl, const f32x4 (&s)[2][4], const char* Vc) {
        const float kj = __builtin_bit_cast(float, (u32)__builtin_amdgcn_readlane((int)kvbits, jjl));
        const float gj = keep_i * kj;
        const int j = j0 + jjl;
        short8 pb[2][2];
        #pragma unroll
        for (int qh = 0; qh < 2; ++qh) {
            f32x4 p4[4];
            #pragma unroll
            for (int n0 = 0; n0 < 4; ++n0)
                #pragma unroll
                for (int r = 0; r < 4; ++r)
                    p4[n0][r] = __builtin_amdgcn_exp2f(s[qh][n0][r]);
            if (j == kq_s) {   // scalar branch: strict upper triangle inside diagonal block
                const int qthis = qloc + qh * 16;
                #pragma unroll
                for (int n0 = 0; n0 < 4; ++n0)
                    #pragma unroll
                    for (int r = 0; r < 4; ++r)
                        if (n0 * 16 + q16 * 4 + r > qthis) p4[n0][r] = 0.f;
            }
            f32x4 sv = (p4[0] + p4[1]) + (p4[2] + p4[3]);
            float sum = (sv[0] + sv[1]) + (sv[2] + sv[3]);
            {   // butterfly over the 4 q16-groups
                u32 sa = __builtin_bit_cast(u32, sum), sb = sa;
                pl16swap(sa, sb);
                sum = __builtin_bit_cast(float, sa) + __builtin_bit_cast(float, sb);
                u32 sc = __builtin_bit_cast(u32, sum), sd = sc;
                pl32swap(sc, sd);
                sum = __builtin_bit_cast(float, sc) + __builtin_bit_cast(float, sd);
            }
            const float rinv = gj * __builtin_amdgcn_rcpf(sum);
            u32 dw[4][2];
            #pragma unroll
            for (int n0 = 0; n0 < 4; ++n0) {
                f32x4 t = p4[n0] * rinv;
                dw[n0][0] = cvt_pk_bf16(t[0], t[1]);
                dw[n0][1] = cvt_pk_bf16(t[2], t[3]);
            }
            #pragma unroll
            for (int kk = 0; kk < 2; ++kk) {
                u32 c0 = dw[2 * kk][0], d0 = dw[2 * kk + 1][0];
                pl32swap(c0, d0);
                pl16swap(c0, d0);
                u32 c1 = dw[2 * kk][1], d1 = dw[2 * kk + 1][1];
                pl32swap(c1, d1);
                pl16swap(c1, d1);
                u32x4 wv;
                wv[0] = c0; wv[1] = c1; wv[2] = d0; wv[3] = d1;
                pb[qh][kk] = __builtin_bit_cast(short8, wv);
            }
        }
        __builtin_amdgcn_s_setprio(1);
        #pragma unroll
        for (int dt = 0; dt < 4; ++dt) {
            short8 va0 = *(const short8*)(Vc + dt * 2048 + lb);
            short8 va1 = *(const short8*)(Vc + dt * 2048 + 1024 + lb);
            #pragma unroll
            for (int qh = 0; qh < 2; ++qh) {
                o[qh][dt] = __builtin_amdgcn_mfma_f32_16x16x32_bf16(va0, pb[qh][0], o[qh][dt], 0, 0, 0);
                o[qh][dt] = __builtin_amdgcn_mfma_f32_16x16x32_bf16(va1, pb[qh][1], o[qh][dt], 0, 0, 0);
            }
        }
        __builtin_amdgcn_s_setprio(0);
    };
    auto WAITBAR = [&]() {
        asm volatile("s_waitcnt vmcnt(0)" ::: "memory");
        __builtin_amdgcn_s_barrier();
        __builtin_amdgcn_sched_barrier(0);
    };
    // rotate rings: K swap; V 3-cycle (vPV<-vNext, vNext<-vStage, vStage<-old vPV)
    auto ROT = [&]() {
        char* t = kRead; kRead = kStage; kStage = t;
        char* u = vPV; vPV = vNext; vNext = vStage; vStage = u;
    };

    // prologue: stage tile0 -> (kStage=smem, vPV=v0), tile1 -> (kRead=smem+8K, vNext=v1)
    STAGE(kStage, vPV);
    STAGE(kRead, vNext);
    asm volatile("s_waitcnt vmcnt(4)" ::: "memory");   // tile 0 resident
    __builtin_amdgcn_s_barrier();

    f32x4 sA[2][4], sB[2][4];
    QK(kStage, sA);   // QK(tile 0) from kStage (holds K(0) until first stage overwrites)

    // main loop: bodies 0 .. nj-3 (2x unrolled, static sA/sB ping-pong)
    for (int jj = 0; jj + 3 < nj; jj += 2) {
        WAITBAR();                        // tile jj+1 resident (all waves)
        STAGE(kStage, vStage);            // tile jj+2; K target's QK reader & V target's PV reader done
        QK(kRead, sB);                    // QK(tile jj+1) — overlaps softmax below
        SMPV(jj, sA, vPV);                // softmax+PV of tile jj
        ROT();
        WAITBAR();
        STAGE(kStage, vStage);            // tile jj+3
        QK(kRead, sA);
        SMPV(jj + 1, sB, vPV);
        ROT();
    }
    // body nj-2: QK(nj-1), no stage (tile nj doesn't exist)
    WAITBAR();
    QK(kRead, sB);
    SMPV(nj - 2, sA, vPV);
    ROT();
    // body nj-1: softmax+PV only
    WAITBAR();
    SMPV(nj - 1, sB, vPV);

    // epilogue: att[q][h*64 + d], d = dt*16 + q16*4 + r -> packed 8B stores
    #pragma unroll
    for (int qh = 0; qh < 2; ++qh) {
        u16* obase = att + (size_t)(i * 128 + wid * 32 + qh * 16 + l16) * 512 + h * 64 + q16 * 4;
        #pragma unroll
        for (int dt = 0; dt < 4; ++dt) {
            u32x2 st;
            st[0] = cvt_pk_bf16(o[qh][dt][0], o[qh][dt][1]);
            st[1] = cvt_pk_bf16(o[qh][dt][2], o[qh][dt][3]);
            *(u32x2*)(obase + dt * 16) = st;
        }
    }
}

// ---------------- workspace layout (bytes) ----------------
// main (ws >= 59M+4K): wqkvT 0..2M | wotT 2..2.5M | keep 2.5M | qb 3..11M | kf 11..19M |
//   vf 19..27M | xb 27..35M (dead after qkv; att3 alias) | att0 35..43M | att1 43..51M | att2 51..59M
// fallback (smaller ws): same through vf; att1 = 27M (xb alias), att0 = 35..43M; peak 43M.
static const size_t OFF_WQKVT = 0;
static const size_t OFF_WOTT  = (size_t)2u << 20;
static const size_t OFF_KEEP  = ((size_t)2u << 20) + (512u << 10);
static const size_t OFF_QB    = (size_t)3u << 20;
static const size_t OFF_KF    = (size_t)11u << 20;
static const size_t OFF_VF    = (size_t)19u << 20;
static const size_t OFF_XB    = (size_t)27u << 20;
static const size_t OFF_P0    = (size_t)35u << 20;
static const size_t OFF_P1    = (size_t)43u << 20;
static const size_t OFF_P2    = (size_t)51u << 20;

extern "C" void kernel_launch(void* const* d_in, const int* in_sizes, int n_in,
                              void* d_out, int out_size, void* d_ws, size_t ws_size,
                              hipStream_t stream) {
    const float* x     = (const float*)d_in[0];
    const float* w_qkv = (const float*)d_in[1];
    const float* b_qkv = (const float*)d_in[2];
    const float* w_out = (const float*)d_in[3];
    const float* b_out = (const float*)d_in[4];
    const float* w_r1  = (const float*)d_in[5];
    const float* b_r1  = (const float*)d_in[6];
    const float* w_r2  = (const float*)d_in[7];
    const float* b_r2  = (const float*)d_in[8];
    float* out = (float*)d_out;
    char* ws = (char*)d_ws;
    u16* wqkvT  = (u16*)(ws + OFF_WQKVT);
    u16* wotT   = (u16*)(ws + OFF_WOTT);
    float* keepf = (float*)(ws + OFF_KEEP);
    u16* qb     = (u16*)(ws + OFF_QB);
    u16* kf     = (u16*)(ws + OFF_KF);
    u16* vf     = (u16*)(ws + OFF_VF);
    u16* xb     = (u16*)(ws + OFF_XB);
    u16* attnb  = (u16*)(ws + OFF_QB);   // alias: qb dead after attn

    const bool big = ws_size >= ((size_t)59u << 20) + 4096;
    const int njh = big ? 4 : 2;
    const int nj  = NBLK / njh;
    // partial buffers per jh (disjoint; jh-last aliases dead xb region)
    u16* a0 = (u16*)(ws + OFF_P0);
    u16* a1 = big ? (u16*)(ws + OFF_P1) : (u16*)(ws + OFF_XB);
    u16* a2 = big ? (u16*)(ws + OFF_P2) : a0;   // unused in fallback
    u16* a3 = big ? (u16*)(ws + OFF_XB) : a0;   // unused in fallback

    cvt_x_kernel<<<4096, 256, 0, stream>>>(x, xb);
    cvt_T_kernel<<<3072, 256, 0, stream>>>(w_qkv, wqkvT, 1536);
    cvt_T_kernel<<<1024, 256, 0, stream>>>(w_out, wotT, 512);
    qkv_gemm<<<dim3(64, 12), 256, 0, stream>>>(xb, wqkvT, b_qkv, qb, kf, vf);
    router_kernel<<<128, 256, 0, stream>>>(qb, w_r1, b_r1, w_r2, b_r2, keepf);
    attn_kernel<<<dim3(8, njh, 64), 256, 0, stream>>>(qb, kf, vf, keepf, a0, a1, a2, a3, nj);
    sum4_kernel<<<2048, 256, 0, stream>>>(a0, a1, a2, a3, njh, attnb);
    out_gemm<<<dim3(64, 4), 256, 0, stream>>>(attnb, wotT, b_out, out);
}